// Round 9
// baseline (304.556 us; speedup 1.0000x reference)
//
#include <hip/hip_runtime.h>

// DVDNMixer: 8-fold PMF convolution (51 atoms -> 401) + C51 projection to 51.
//
// Projection is exact-integer: support=linspace(-80,80,401), delta=0.4 =>
//   out[0] = sum q[0..175]; out[j] = q[175+j] (1<=j<=49); out[50] = sum q[225..400]
//
// One wave per (b,t) task; per-wave zero-padded LDS ping-pong buffers (no
// __syncthreads, no explicit waitcnt: per-wave DS ops execute in order and
// volatile forbids compile-time reordering among LDS accesses).
//
// R4 post-mortem (177us, VALUBusy 51%): per-step p[] s_loads share lgkmcnt
// with ds_read, and SMEM completes OUT OF ORDER vs DS => compiler must drain
// lgkmcnt(0) before each step's FMAs — a full flush 7x/task. FIX: p[] now
// per-lane GLOBAL vector loads (vmcnt counter, hardware broadcast of the
// wave-uniform address). Pointer laundered through an opaque zero VGPR so
// uniformity analysis can't re-scalarize to s_load. LDS waits become counted
// lgkmcnt(N); p latency hides under hoisting + counted vmcnt.
// Agent bases are 204*a bytes (4B-aligned only) => phase-templated loads:
// LEAD scalar dwords to 16B alignment, then 12x dwordx4, then tail scalars.
//
//   - window loads stay VOLATILE f4 LDS reads => ds_read_b128, window pinned
//     in VGPRs (R1 post-mortem: non-volatile remat'd to per-use ds_read_b32)
//   - linear layout: R=4 window reads 2-way (free), R=8 4-way (1.58x);
//     conflicts measured 6.9e6 cy ~ 6% of CU-cycles — acceptable
//   - outputs beyond L_out compute to exact zeros (zero-padded windows) =>
//     unguarded writes; zero-invariants hold inductively
// Step 7 keeps results in registers and feeds the projection directly.

typedef float f4 __attribute__((ext_vector_type(4)));

#define N_ATOM  51
#define N_TASKS 32768            // BS*T = 128*256
#define WPB     4
#define PAD     52               // left zero pad, floats (16B multiple)
#define BUFSZ   576              // floats; max read = lane63,R=8: 504+60=564

// 51 wave-uniform floats via per-lane vector loads. PH = gp float-offset mod 4.
template<int PH>
__device__ __forceinline__ void load_p(const float* gpz, float* p) {
  constexpr int LEAD = (4 - PH) & 3;         // scalars to reach 16B alignment
#pragma unroll
  for (int l = 0; l < LEAD; ++l) p[l] = gpz[l];
#pragma unroll
  for (int m = 0; m < 12; ++m) {             // 12 aligned dwordx4
    f4 v = *(const f4*)(gpz + LEAD + 4 * m);
    p[LEAD + 4 * m + 0] = v.x; p[LEAD + 4 * m + 1] = v.y;
    p[LEAD + 4 * m + 2] = v.z; p[LEAD + 4 * m + 3] = v.w;
  }
#pragma unroll
  for (int t = LEAD + 48; t < N_ATOM; ++t) p[t] = gpz[t];   // tail scalars
}

// acc[0..R) = conv outputs at positions lane*R + r of (q_in (*) p).
// q[k] at bin[PAD+k]; window W[x] = bin[lane*R + x]; FMA uses W[PAD+r-j],
// index range [2, R+51] within [0, 4*NW).
template<int R, int PH>
__device__ __forceinline__ void conv_body(const float* gpz,
                                          const float* bin, float* acc, int lane) {
  constexpr int NW = (R + PAD) / 4;          // 14 (R=4) / 15 (R=8)
  const int o0 = lane * R;                   // 16B-aligned (R%4==0)
  float W[NW * 4];
#pragma unroll
  for (int m = 0; m < NW; ++m) {
    f4 v = *(const volatile f4*)(bin + o0 + 4 * m);   // one base + offset:
    W[4 * m + 0] = v.x; W[4 * m + 1] = v.y;
    W[4 * m + 2] = v.z; W[4 * m + 3] = v.w;
  }
  float p[N_ATOM];
  load_p<PH>(gpz, p);                        // VMEM broadcast loads (vmcnt)
#pragma unroll
  for (int r = 0; r < R; ++r) acc[r] = 0.f;
#pragma unroll
  for (int j = 0; j < N_ATOM; ++j)           // p[j] dead after its r-group
#pragma unroll
    for (int r = 0; r < R; ++r)
      acc[r] = fmaf(p[j], W[PAD + r - j], acc[r]);
}

template<int R, int PH>
__device__ __forceinline__ void conv_step(const float* gpz,
                                          const float* bin, float* bout, int lane) {
  float acc[R];
  conv_body<R, PH>(gpz, bin, acc, lane);
#pragma unroll
  for (int r4 = 0; r4 < R / 4; ++r4) {
    f4 v = { acc[4 * r4 + 0], acc[4 * r4 + 1], acc[4 * r4 + 2], acc[4 * r4 + 3] };
    *(volatile f4*)(bout + PAD + lane * R + 4 * r4) = v;
  }
}

__global__ __launch_bounds__(256)
void dvdn_mixer_kernel(const float* __restrict__ in, float* __restrict__ out) {
  __shared__ __align__(16) float buf[WPB][2][BUFSZ];
  const int lane = threadIdx.x & 63;
  const int wave = threadIdx.x >> 6;
  const int task = __builtin_amdgcn_readfirstlane(blockIdx.x * WPB + wave);

  // Opaque zero in a VGPR: defeats uniformity analysis so p-loads stay VMEM
  // (s_load would share out-of-order lgkmcnt with ds_read => forced drains).
  int lz = 0;
  asm volatile("" : "+v"(lz));
  const float* gp = in + lz + (size_t)task * (8 * N_ATOM);

  float* b0 = buf[wave][0];
  float* b1 = buf[wave][1];

  // Init b0 = {zeros, agent0 at [PAD,PAD+51)}. Regions of b0 beyond
  // [PAD,PAD+256) are never re-written by R=4 steps, so init zeros serve
  // steps 5/7's wider windows (step6 R=8 rewrites [PAD,PAD+512) before
  // step7 reads; [PAD+512,576) stays init-zero for step7's tail window).
#pragma unroll
  for (int k = lane; k < BUFSZ / 4; k += 64) {
    const int f = 4 * k - PAD;               // agent0 q-index of component .x
    f4 v = { 0.f, 0.f, 0.f, 0.f };
    if (f >= 0 && f + 3 < N_ATOM) {
      f4 g = *(const f4*)(gp + f);           // agent0 is 16B-aligned (phase 0)
      v = g;
    } else if (f + 3 >= 0 && f < N_ATOM) {
      if (f >= 0)                       v.x = gp[f];
      if (f + 1 >= 0 && f + 1 < N_ATOM) v.y = gp[f + 1];
      if (f + 2 >= 0 && f + 2 < N_ATOM) v.z = gp[f + 2];
      if (f + 3 < N_ATOM)               v.w = gp[f + 3];
    }
    *(volatile f4*)(b0 + 4 * k) = v;
  }
  // Init b1: left pad only (all other read regions of b1 are written by the
  // preceding step first: step5 R=8 covers [PAD,PAD+512) > max read 564).
  if (lane < PAD / 4) {
    f4 z = { 0.f, 0.f, 0.f, 0.f };
    *(volatile f4*)(b1 + 4 * lane) = z;
  }

  // L_out: 101,151,201,251 (R=4) ; 301,351 (R=8) ; 401 in registers (last).
  // Phase of agent a = (51*a) % 4 = (3a) & 3.
  conv_step<4, 3>(gp + 1 * N_ATOM, b0, b1, lane);
  conv_step<4, 2>(gp + 2 * N_ATOM, b1, b0, lane);
  conv_step<4, 1>(gp + 3 * N_ATOM, b0, b1, lane);
  conv_step<4, 0>(gp + 4 * N_ATOM, b1, b0, lane);
  conv_step<8, 3>(gp + 5 * N_ATOM, b0, b1, lane);
  conv_step<8, 2>(gp + 6 * N_ATOM, b1, b0, lane);

  float acc[8];
  conv_body<8, 1>(gp + 7 * N_ATOM, b0, acc, lane);

  // Projection epilogue; q beyond 400 is exact 0 so unguarded sums are safe.
  float s0 = 0.f, s1 = 0.f;
  float* o = out + (size_t)task * N_ATOM;
#pragma unroll
  for (int r = 0; r < 8; ++r) {
    const int oidx = 8 * lane + r;           // 0..511
    if (oidx >= 176 && oidx < 225) o[oidx - 175] = acc[r];
    s0 += (oidx < 176) ? acc[r] : 0.f;
    s1 += (oidx >= 225) ? acc[r] : 0.f;
  }
#pragma unroll
  for (int d = 1; d < 64; d <<= 1) {
    s0 += __shfl_xor(s0, d, 64);
    s1 += __shfl_xor(s1, d, 64);
  }
  if (lane == 0) { o[0] = s0; o[50] = s1; }
}

extern "C" void kernel_launch(void* const* d_in, const int* in_sizes, int n_in,
                              void* d_out, int out_size, void* d_ws, size_t ws_size,
                              hipStream_t stream) {
  const float* agent_qs = (const float*)d_in[0];  // [128,256,8,51] f32
  // d_in[1] (states) is unused by the reference computation
  float* out = (float*)d_out;                     // [128,256,51] f32
  dvdn_mixer_kernel<<<N_TASKS / WPB, 256, 0, stream>>>(agent_qs, out);
}